// Round 4
// baseline (332.987 us; speedup 1.0000x reference)
//
#include <hip/hip_runtime.h>
#include <stdint.h>

typedef __bf16 bf16x8 __attribute__((ext_vector_type(8)));
typedef float f32x4 __attribute__((ext_vector_type(4)));
typedef unsigned short ushort8 __attribute__((ext_vector_type(8)));

#define S_DIM 1024
#define R_DIM 256
#define DMODEL 256
#define EPSV 9.5367431640625e-07f
#define ASTRIDE 264  // 256 + 8 bf16 pad -> row advance 4 banks
#define OSTRIDE 72   // 64 + 8 pad: 144B rows (16B-aligned), column reads conflict-free

__device__ __forceinline__ unsigned short f2bf(float f) {
  uint32_t u = __float_as_uint(f);
  u += 0x7fffu + ((u >> 16) & 1u);
  return (unsigned short)(u >> 16);
}
__device__ __forceinline__ float bf2f(unsigned short s) {
  return __uint_as_float(((uint32_t)s) << 16);
}
__device__ __forceinline__ bf16x8 ldfrag(const unsigned short* p) {
  return __builtin_bit_cast(bf16x8, *(const ushort8*)p);
}
__device__ __forceinline__ bf16x8 pack8(float4 a, float4 b) {
  ushort8 u;
  u[0] = f2bf(a.x); u[1] = f2bf(a.y); u[2] = f2bf(a.z); u[3] = f2bf(a.w);
  u[4] = f2bf(b.x); u[5] = f2bf(b.y); u[6] = f2bf(b.z); u[7] = f2bf(b.w);
  return __builtin_bit_cast(bf16x8, u);
}

// ---------- all weight packing in one launch ----------
// B-frag layout: elem j of lane l for (kstep,ct) = W[kstep*32+(l>>4)*8+j][ct*16+(l&15)]
__global__ __launch_bounds__(256) void pack_all_kernel(const float* __restrict__ Wk,
                                                       const float* __restrict__ Wv,
                                                       const float* __restrict__ Wg,
                                                       const float* __restrict__ Wo,
                                                       unsigned short* __restrict__ wkv,
                                                       unsigned short* __restrict__ wg_p,
                                                       unsigned short* __restrict__ wo_p) {
  int bid = blockIdx.x;
  int tid = threadIdx.x;
  if (bid < 64) {
    int idx = bid * 256 + tid;
    int j = idx & 7, lane = (idx >> 3) & 63, t = idx >> 9;
    int ct = t & 3, kstep = t >> 2;
    int k = kstep * 32 + ((lane >> 4) << 3) + j;
    int col = ct * 16 + (lane & 15);
    float w = (col < 32) ? Wk[k * 32 + col] : Wv[k * 32 + (col - 32)];
    wkv[idx] = f2bf(w);
  } else {
    const float* W = (bid < 320) ? Wg : Wo;
    unsigned short* out = (bid < 320) ? wg_p : wo_p;
    int idx = ((bid < 320) ? (bid - 64) : (bid - 320)) * 256 + tid;
    int j = idx & 7, lane = (idx >> 3) & 63, t = idx >> 9;
    int ct = t & 15, kstep = t >> 4;
    int k = kstep * 32 + ((lane >> 4) << 3) + j;
    int col = ct * 16 + (lane & 15);
    out[idx] = f2bf(W[k * 256 + col]);
  }
}

// ---------- fused streaming pass: kv projection (blocks 0..4095, LDS-staged) + masked pool ----------
template <int USE_ECHO>
__global__ __launch_bounds__(256) void streams_kernel(const float* __restrict__ m_data,
                                                      const unsigned short* __restrict__ wkv,
                                                      unsigned short* __restrict__ kb,
                                                      unsigned short* __restrict__ vb_t,
                                                      const float* __restrict__ q_data,
                                                      const float* __restrict__ q_mask,
                                                      float* __restrict__ psum,
                                                      float* __restrict__ pmask,
                                                      unsigned short* __restrict__ qb16) {
  __shared__ __align__(16) char smem_raw[64 * ASTRIDE * 2 + 64 * OSTRIDE * 2];
  int bid = blockIdx.x;
  int tid = threadIdx.x;
  if (bid < 4096) {
    // ----- kv projection: rows bid*64 .. +63, coalesced LDS staging -----
    unsigned short* As = (unsigned short*)smem_raw;                      // [64][ASTRIDE]
    unsigned short* O  = (unsigned short*)(smem_raw + 64 * ASTRIDE * 2); // [64][OSTRIDE]
    int wave = tid >> 6, lane = tid & 63;
    int g = lane >> 4, lr = lane & 15;
    int row0 = bid * 64;
    // stage: 2048 chunks of 8 bf16, fully coalesced fp32 reads
    #pragma unroll
    for (int i = 0; i < 8; i++) {
      int c = i * 256 + tid;
      int ra = c >> 5, cc = c & 31;
      const float4* p = (const float4*)&m_data[(size_t)(row0 + ra) * DMODEL + cc * 8];
      *(ushort8*)&As[ra * ASTRIDE + cc * 8] = __builtin_bit_cast(ushort8, pack8(p[0], p[1]));
    }
    __syncthreads();
    // MFMA: wave w owns row-tile w (16 rows); A from LDS, B (wkv) from L1/L2
    f32x4 acc[4] = {};
    #pragma unroll
    for (int ks = 0; ks < 8; ks++) {
      bf16x8 af = ldfrag(&As[(wave * 16 + lr) * ASTRIDE + ks * 32 + g * 8]);
      #pragma unroll
      for (int ct = 0; ct < 4; ct++) {
        bf16x8 bf = ldfrag(&wkv[((ks * 4 + ct) << 9) + lane * 8]);
        acc[ct] = __builtin_amdgcn_mfma_f32_16x16x32_bf16(af, bf, acc[ct], 0, 0, 0);
      }
    }
    // epilogue -> LDS out tile [64][OSTRIDE]
    #pragma unroll
    for (int ct = 0; ct < 4; ct++) {
      #pragma unroll
      for (int rg = 0; rg < 4; rg++) {
        O[(wave * 16 + g * 4 + rg) * OSTRIDE + ct * 16 + lr] = f2bf(acc[ct][rg]);  // D layout (m89)
      }
    }
    __syncthreads();
    // coalesced write-out: kb tile is contiguous 4KB; vb_t tile is 32 rows x 128B
    {
      int rowl = tid >> 2, c8 = (tid & 3) * 8;  // kb: cols 0..31
      ushort8 v = *(const ushort8*)&O[rowl * OSTRIDE + c8];
      *(ushort8*)&kb[(size_t)(row0 + rowl) * 32 + c8] = v;
    }
    {
      int d = tid >> 3, s8 = (tid & 7) * 8;     // vb_t: d 0..31, s-chunk of 8
      ushort8 v;
      #pragma unroll
      for (int j = 0; j < 8; j++) v[j] = O[(s8 + j) * OSTRIDE + 32 + d];
      int ra = row0 >> 10, sl0 = row0 & 1023;
      *(ushort8*)&vb_t[((size_t)(ra * 32) + d) * S_DIM + sl0 + s8] = v;
    }
  } else {
    // ----- masked mean pool partials + bf16 echo -----
    float* mlds = (float*)smem_raw;
    float* wred = (float*)(smem_raw + 256 * 4);
    int b2 = bid - 4096;
    int r = b2 >> 2, c = b2 & 3;
    int s0 = c * 256;
    float m = q_mask[r * S_DIM + s0 + tid];
    mlds[tid] = m;
    float ms = m;
    for (int off = 32; off; off >>= 1) ms += __shfl_down(ms, off);
    if ((tid & 63) == 0) wred[tid >> 6] = ms;
    __syncthreads();
    if (tid == 0) pmask[r * 4 + c] = wred[0] + wred[1] + wred[2] + wred[3];
    float acc = 0.f;
    size_t rowbase = (size_t)(r * S_DIM + s0);
    const float* base = q_data + rowbase * DMODEL + tid;
    if (USE_ECHO) {
      unsigned short* eb = qb16 + rowbase * DMODEL + tid;
      #pragma unroll 4
      for (int s = 0; s < 256; s++) {
        float v = base[(size_t)s * DMODEL];
        acc += v * mlds[s];
        eb[(size_t)s * DMODEL] = f2bf(v);
      }
    } else {
      #pragma unroll 4
      for (int s = 0; s < 256; s++) acc += base[(size_t)s * DMODEL] * mlds[s];
    }
    psum[(r * 4 + c) * 256 + tid] = acc;
  }
}

// ---------- attn2: pool2 (q projection) + QK^T MFMA + softmax + PV MFMA, one block per r ----------
__global__ __launch_bounds__(256) void attn2_kernel(const unsigned short* __restrict__ kb,
                                                    const unsigned short* __restrict__ vb_t,
                                                    const float* __restrict__ psum,
                                                    const float* __restrict__ pmask,
                                                    const float* __restrict__ Wq,
                                                    const float* __restrict__ bias,
                                                    float* __restrict__ wavg) {
  int r = blockIdx.x, tid = threadIdx.x;
  int w = tid >> 6, lane = tid & 63, g = lane >> 4, lr = lane & 15;
  __shared__ float qa[256];
  __shared__ float qsp[8 * 33];      // padded q[h][k]
  __shared__ float lgp[8 * 1028];    // padded logits/P [h][s]
  __shared__ float paccL[8 * 64 * 4];
  __shared__ float denom[8];
  // ---- pool2: q_avg -> q projection (qproj kept in LDS only) ----
  float s4 = psum[(r * 4 + 0) * 256 + tid] + psum[(r * 4 + 1) * 256 + tid] +
             psum[(r * 4 + 2) * 256 + tid] + psum[(r * 4 + 3) * 256 + tid];
  float msum = pmask[r * 4] + pmask[r * 4 + 1] + pmask[r * 4 + 2] + pmask[r * 4 + 3];
  qa[tid] = s4 / (msum + EPSV);
  __syncthreads();
  float qacc = 0.f;
  #pragma unroll 8
  for (int d = 0; d < 256; d++) qacc += qa[d] * Wq[d * 256 + tid];
  qsp[(tid >> 5) * 33 + (tid & 31)] = qacc * 0.17677669529663687f;  // h=tid>>5, k=tid&31
  __syncthreads();
  // ---- QK^T via MFMA: A = K rows [s][k], B = q [k][h] ----
  ushort8 uq;
  #pragma unroll
  for (int j = 0; j < 8; j++)
    uq[j] = (lr < 8) ? f2bf(qsp[lr * 33 + g * 8 + j]) : (unsigned short)0;
  bf16x8 qf = __builtin_bit_cast(bf16x8, uq);
  for (int i = 0; i < 16; i++) {
    int rt = w * 16 + i;
    bf16x8 af = ldfrag(&kb[((size_t)r * S_DIM + rt * 16 + lr) * 32 + g * 8]);
    f32x4 d4 = {};
    d4 = __builtin_amdgcn_mfma_f32_16x16x32_bf16(af, qf, d4, 0, 0, 0);
    if (lr < 8) {
      #pragma unroll
      for (int rg = 0; rg < 4; rg++) {
        int sv = rt * 16 + g * 4 + rg;   // D: row=s=(lane>>4)*4+reg, col=h=lane&15
        lgp[lr * 1028 + sv] = d4[rg] + bias[r * S_DIM + sv];
      }
    }
  }
  __syncthreads();
  // ---- softmax per head (wave w handles h = 2w, 2w+1) ----
  for (int hh = 0; hh < 2; hh++) {
    int h = w * 2 + hh;
    float mx = -1e30f;
    #pragma unroll
    for (int i = 0; i < 16; i++) mx = fmaxf(mx, lgp[h * 1028 + lane + i * 64]);
    for (int off = 32; off; off >>= 1) mx = fmaxf(mx, __shfl_xor(mx, off));
    float sum = 0.f;
    #pragma unroll
    for (int i = 0; i < 16; i++) {
      float e = __expf(lgp[h * 1028 + lane + i * 64] - mx);
      lgp[h * 1028 + lane + i * 64] = e;
      sum += e;
    }
    for (int off = 32; off; off >>= 1) sum += __shfl_xor(sum, off);
    if (lane == 0) denom[h] = sum;
  }
  __syncthreads();
  // ---- PV via MFMA: A = P [h][s], B = V_t [s][d]; wave w does ks = 8w..8w+7 ----
  f32x4 pv[2] = {};
  for (int kk = 0; kk < 8; kk++) {
    int ks = w * 8 + kk;
    bf16x8 pa;
    if (lr < 8) {
      const float4* pp = (const float4*)&lgp[lr * 1028 + ks * 32 + g * 8];
      pa = pack8(*(const float4*)&pp[0], *(const float4*)&pp[1]);
    } else {
      pa = __builtin_bit_cast(bf16x8, (ushort8)(unsigned short)0);
    }
    #pragma unroll
    for (int ct = 0; ct < 2; ct++) {
      bf16x8 vf = ldfrag(&vb_t[((size_t)(r * 32) + ct * 16 + lr) * S_DIM + ks * 32 + g * 8]);
      pv[ct] = __builtin_amdgcn_mfma_f32_16x16x32_bf16(pa, vf, pv[ct], 0, 0, 0);
    }
  }
  *(f32x4*)&paccL[((w * 2 + 0) * 64 + lane) * 4] = pv[0];
  *(f32x4*)&paccL[((w * 2 + 1) * 64 + lane) * 4] = pv[1];
  __syncthreads();
  // ---- cross-wave reduce + divide ----
  {
    int h = tid >> 5, d = tid & 31;
    int ct = d >> 4, l2 = (h >> 2) * 16 + (d & 15), rg = h & 3;
    float sum = 0.f;
    #pragma unroll
    for (int w4 = 0; w4 < 4; w4++) sum += paccL[((w4 * 2 + ct) * 64 + l2) * 4 + rg];
    wavg[r * 256 + tid] = __fdividef(sum, denom[h]);
  }
}

// ---------- gate3: 64-row tiles, B from L2 per k-step ----------
template <int USE_BF16>
__global__ __launch_bounds__(512, 4) void gate3_kernel(const float* __restrict__ q_data,
                                                       const unsigned short* __restrict__ qb16,
                                                       const unsigned short* __restrict__ wg,
                                                       const unsigned short* __restrict__ wo,
                                                       const float* __restrict__ bgv,
                                                       const float* __restrict__ bov,
                                                       const float* __restrict__ wavg,
                                                       float* __restrict__ outp) {
  __shared__ unsigned short AsG[64 * ASTRIDE];
  __shared__ float wavs[256];
  __shared__ float bgs[256];
  __shared__ float bos[256];
  int bid = blockIdx.x;
  int r = bid >> 4, sc = bid & 15;
  int tid = threadIdx.x;
  int wave = tid >> 6, lane = tid & 63, g = lane >> 4, lr = lane & 15;
  int row0g = r * S_DIM + sc * 64;
  if (tid < 256) {
    wavs[tid] = wavg[r * 256 + tid];
    bgs[tid] = bgv[tid];
    bos[tid] = bov[tid];
  }
  // stage A tile (64 rows x 256 bf16): 2048 x 16B chunks
  #pragma unroll
  for (int i = 0; i < 4; i++) {
    int c = i * 512 + tid;
    int ra = c >> 5, cc = c & 31;
    ushort8 v;
    if (USE_BF16) {
      v = *(const ushort8*)&qb16[(size_t)(row0g + ra) * DMODEL + cc * 8];
    } else {
      const float4* p = (const float4*)&q_data[(size_t)(row0g + ra) * DMODEL + cc * 8];
      v = __builtin_bit_cast(ushort8, pack8(p[0], p[1]));
    }
    *(ushort8*)&AsG[ra * ASTRIDE + cc * 8] = v;
  }
  __syncthreads();
  // GEMM1: X @ Wg ; wave owns ct = 2*wave, 2*wave+1; B streamed from L2
  f32x4 acc[4][2] = {};
  for (int ks = 0; ks < 8; ks++) {
    bf16x8 b0 = ldfrag(&wg[((ks * 16 + 2 * wave) << 9) + lane * 8]);
    bf16x8 b1 = ldfrag(&wg[((ks * 16 + 2 * wave + 1) << 9) + lane * 8]);
    bf16x8 af[4];
    #pragma unroll
    for (int rt = 0; rt < 4; rt++)
      af[rt] = ldfrag(&AsG[(rt * 16 + lr) * ASTRIDE + ks * 32 + g * 8]);
    #pragma unroll
    for (int rt = 0; rt < 4; rt++) {
      acc[rt][0] = __builtin_amdgcn_mfma_f32_16x16x32_bf16(af[rt], b0, acc[rt][0], 0, 0, 0);
      acc[rt][1] = __builtin_amdgcn_mfma_f32_16x16x32_bf16(af[rt], b1, acc[rt][1], 0, 0, 0);
    }
  }
  __syncthreads();  // all GEMM1 reads of AsG done
  // gating epilogue -> G overwrites AsG
  #pragma unroll
  for (int rt = 0; rt < 4; rt++) {
    #pragma unroll
    for (int c0 = 0; c0 < 2; c0++) {
      int col = (wave * 2 + c0) * 16 + lr;
      float wv = wavs[col];
      float bgc = bgs[col];
      #pragma unroll
      for (int rg = 0; rg < 4; rg++) {
        int row = rt * 16 + g * 4 + rg;
        float x = acc[rt][c0][rg] + bgc;
        float sg = __fdividef(1.0f, 1.0f + __expf(-x));
        AsG[row * ASTRIDE + col] = f2bf(sg * wv);
      }
    }
  }
  __syncthreads();
  // GEMM2: G @ Wo
  f32x4 acc2[4][2] = {};
  for (int ks = 0; ks < 8; ks++) {
    bf16x8 b0 = ldfrag(&wo[((ks * 16 + 2 * wave) << 9) + lane * 8]);
    bf16x8 b1 = ldfrag(&wo[((ks * 16 + 2 * wave + 1) << 9) + lane * 8]);
    bf16x8 af[4];
    #pragma unroll
    for (int rt = 0; rt < 4; rt++)
      af[rt] = ldfrag(&AsG[(rt * 16 + lr) * ASTRIDE + ks * 32 + g * 8]);
    #pragma unroll
    for (int rt = 0; rt < 4; rt++) {
      acc2[rt][0] = __builtin_amdgcn_mfma_f32_16x16x32_bf16(af[rt], b0, acc2[rt][0], 0, 0, 0);
      acc2[rt][1] = __builtin_amdgcn_mfma_f32_16x16x32_bf16(af[rt], b1, acc2[rt][1], 0, 0, 0);
    }
  }
  #pragma unroll
  for (int rt = 0; rt < 4; rt++) {
    #pragma unroll
    for (int c0 = 0; c0 < 2; c0++) {
      int col = (wave * 2 + c0) * 16 + lr;
      float boc = bos[col];
      #pragma unroll
      for (int rg = 0; rg < 4; rg++) {
        int row = rt * 16 + g * 4 + rg;
        outp[(size_t)(row0g + row) * DMODEL + col] = acc2[rt][c0][rg] + boc;
      }
    }
  }
}

extern "C" void kernel_launch(void* const* d_in, const int* in_sizes, int n_in,
                              void* d_out, int out_size, void* d_ws, size_t ws_size,
                              hipStream_t stream) {
  const float* q_data = (const float*)d_in[0];
  const float* m_data = (const float*)d_in[1];
  const float* q_mask = (const float*)d_in[2];
  const float* bias   = (const float*)d_in[3];
  const float* Wq     = (const float*)d_in[4];
  const float* Wk     = (const float*)d_in[5];
  const float* Wv     = (const float*)d_in[6];
  const float* Wo     = (const float*)d_in[7];
  const float* bo     = (const float*)d_in[8];
  const float* Wg     = (const float*)d_in[9];
  const float* bg     = (const float*)d_in[10];
  float* outp = (float*)d_out;

  char* ws = (char*)d_ws;
  unsigned short* kb      = (unsigned short*)(ws + 0);          // 16 MB
  unsigned short* vb_t    = (unsigned short*)(ws + 16777216);   // 16 MB (transposed [r][d][s])
  unsigned short* wkv     = (unsigned short*)(ws + 33554432);   // 32 KB
  unsigned short* wg_pack = (unsigned short*)(ws + 33587200);   // 128 KB
  unsigned short* wo_pack = (unsigned short*)(ws + 33718272);   // 128 KB
  float* psum  = (float*)(ws + 33849344);                       // 1 MB
  float* pmask = (float*)(ws + 34897920);                       // 4 KB
  float* wavg  = (float*)(ws + 35164160);                       // 256 KB
  const size_t QB16_OFF = 35651584;
  const size_t QB16_BYTES = (size_t)R_DIM * S_DIM * DMODEL * 2; // 134 MB
  bool use_echo = ws_size >= QB16_OFF + QB16_BYTES;
  unsigned short* qb16 = use_echo ? (unsigned short*)(ws + QB16_OFF) : nullptr;

  pack_all_kernel<<<576, 256, 0, stream>>>(Wk, Wv, Wg, Wo, wkv, wg_pack, wo_pack);
  if (use_echo)
    streams_kernel<1><<<5120, 256, 0, stream>>>(m_data, wkv, kb, vb_t, q_data, q_mask, psum, pmask, qb16);
  else
    streams_kernel<0><<<5120, 256, 0, stream>>>(m_data, wkv, kb, vb_t, q_data, q_mask, psum, pmask, nullptr);
  attn2_kernel<<<256, 256, 0, stream>>>(kb, vb_t, psum, pmask, Wq, bias, wavg);
  if (use_echo)
    gate3_kernel<1><<<4096, 512, 0, stream>>>(q_data, qb16, wg_pack, wo_pack, bg, bo, wavg, outp);
  else
    gate3_kernel<0><<<4096, 512, 0, stream>>>(q_data, nullptr, wg_pack, wo_pack, bg, bo, wavg, outp);
}

// Round 6
// 303.179 us; speedup vs baseline: 1.0983x; 1.0983x over previous
//
#include <hip/hip_runtime.h>
#include <stdint.h>

typedef __bf16 bf16x8 __attribute__((ext_vector_type(8)));
typedef float f32x4 __attribute__((ext_vector_type(4)));
typedef unsigned short ushort8 __attribute__((ext_vector_type(8)));
typedef unsigned short u16x4 __attribute__((ext_vector_type(4)));

#define S_DIM 1024
#define R_DIM 256
#define DMODEL 256
#define EPSV 9.5367431640625e-07f
#define ASTRIDE 264  // 256 + 8 bf16 pad -> row advance 4 banks (2-way, free)
#define OSTRIDE 72   // 64 + 8 pad: column reads conflict-free

__device__ __forceinline__ unsigned short f2bf(float f) {
  uint32_t u = __float_as_uint(f);
  u += 0x7fffu + ((u >> 16) & 1u);
  return (unsigned short)(u >> 16);
}
__device__ __forceinline__ float bf2f(unsigned short s) {
  return __uint_as_float(((uint32_t)s) << 16);
}
__device__ __forceinline__ bf16x8 ldfrag(const unsigned short* p) {
  return __builtin_bit_cast(bf16x8, *(const ushort8*)p);
}
__device__ __forceinline__ bf16x8 pack8(float4 a, float4 b) {
  ushort8 u;
  u[0] = f2bf(a.x); u[1] = f2bf(a.y); u[2] = f2bf(a.z); u[3] = f2bf(a.w);
  u[4] = f2bf(b.x); u[5] = f2bf(b.y); u[6] = f2bf(b.z); u[7] = f2bf(b.w);
  return __builtin_bit_cast(bf16x8, u);
}

// ---------- all weight packing in one launch ----------
// B-frag layout: elem j of lane l for (kstep,ct) = W[kstep*32+(l>>4)*8+j][ct*16+(l&15)]
__global__ __launch_bounds__(256) void pack_all_kernel(const float* __restrict__ Wk,
                                                       const float* __restrict__ Wv,
                                                       const float* __restrict__ Wg,
                                                       const float* __restrict__ Wo,
                                                       unsigned short* __restrict__ wkv,
                                                       unsigned short* __restrict__ wg_p,
                                                       unsigned short* __restrict__ wo_p) {
  int bid = blockIdx.x;
  int tid = threadIdx.x;
  if (bid < 64) {
    int idx = bid * 256 + tid;
    int j = idx & 7, lane = (idx >> 3) & 63, t = idx >> 9;
    int ct = t & 3, kstep = t >> 2;
    int k = kstep * 32 + ((lane >> 4) << 3) + j;
    int col = ct * 16 + (lane & 15);
    float w = (col < 32) ? Wk[k * 32 + col] : Wv[k * 32 + (col - 32)];
    wkv[idx] = f2bf(w);
  } else {
    const float* W = (bid < 320) ? Wg : Wo;
    unsigned short* out = (bid < 320) ? wg_p : wo_p;
    int idx = ((bid < 320) ? (bid - 64) : (bid - 320)) * 256 + tid;
    int j = idx & 7, lane = (idx >> 3) & 63, t = idx >> 9;
    int ct = t & 15, kstep = t >> 4;
    int k = kstep * 32 + ((lane >> 4) << 3) + j;
    int col = ct * 16 + (lane & 15);
    out[idx] = f2bf(W[k * 256 + col]);
  }
}

// ---------- fused streaming pass ----------
// blocks 0..1023: masked mean pool partials + bf16 echo (ILP-8 float4 reads)
// blocks 1024..5119: kv projection, LDS-staged, A-tile LDS reused for out-bounce
template <int USE_ECHO>
__global__ __launch_bounds__(256) void streams_kernel(const float* __restrict__ m_data,
                                                      const unsigned short* __restrict__ wkv,
                                                      unsigned short* __restrict__ kb,
                                                      unsigned short* __restrict__ vb_t,
                                                      const float* __restrict__ q_data,
                                                      const float* __restrict__ q_mask,
                                                      float* __restrict__ psum,
                                                      float* __restrict__ pmask,
                                                      unsigned short* __restrict__ qb16) {
  __shared__ __align__(16) char smem_raw[64 * ASTRIDE * 2];  // 33792 B
  int bid = blockIdx.x;
  int tid = threadIdx.x;
  if (bid < 1024) {
    // ----- masked mean pool: r = bid>>2, s-chunk = bid&3 (256 rows) -----
    float* mlds = (float*)smem_raw;                 // 256 f32
    float* wred = (float*)(smem_raw + 1024);        // 4 f32
    f32x4* red  = (f32x4*)(smem_raw + 2048);        // [4][64] f32x4
    int r = bid >> 2, c = bid & 3;
    int s0 = c * 256;
    float m = q_mask[r * S_DIM + s0 + tid];
    mlds[tid] = m;
    float ms = m;
    for (int off = 32; off; off >>= 1) ms += __shfl_down(ms, off);
    if ((tid & 63) == 0) wred[tid >> 6] = ms;
    __syncthreads();
    if (tid == 0) pmask[r * 4 + c] = wred[0] + wred[1] + wred[2] + wred[3];
    int wv = tid >> 6, ln = tid & 63;
    size_t rowbase = (size_t)(r * S_DIM + s0);
    const float* bp = q_data + (rowbase + wv) * DMODEL + ln * 4;
    f32x4 acc4 = {};
    if (USE_ECHO) {
      unsigned short* ebp = qb16 + (rowbase + wv) * DMODEL + ln * 4;
      #pragma unroll 8
      for (int it = 0; it < 64; it++) {
        float4 v = *(const float4*)(bp + (size_t)it * 4 * DMODEL);
        float mm = mlds[it * 4 + wv];
        acc4[0] += v.x * mm; acc4[1] += v.y * mm;
        acc4[2] += v.z * mm; acc4[3] += v.w * mm;
        u16x4 e;
        e[0] = f2bf(v.x); e[1] = f2bf(v.y); e[2] = f2bf(v.z); e[3] = f2bf(v.w);
        *(u16x4*)(ebp + (size_t)it * 4 * DMODEL) = e;
      }
    } else {
      #pragma unroll 8
      for (int it = 0; it < 64; it++) {
        float4 v = *(const float4*)(bp + (size_t)it * 4 * DMODEL);
        float mm = mlds[it * 4 + wv];
        acc4[0] += v.x * mm; acc4[1] += v.y * mm;
        acc4[2] += v.z * mm; acc4[3] += v.w * mm;
      }
    }
    red[wv * 64 + ln] = acc4;
    __syncthreads();
    int c4 = tid >> 2, cm = tid & 3;
    float sum = red[0 * 64 + c4][cm] + red[1 * 64 + c4][cm] +
                red[2 * 64 + c4][cm] + red[3 * 64 + c4][cm];
    psum[(r * 4 + c) * 256 + tid] = sum;
  } else {
    // ----- kv projection: rows (bid-1024)*64 .. +63 -----
    unsigned short* As = (unsigned short*)smem_raw;   // [64][ASTRIDE]; reused as O [64][OSTRIDE]
    int wave = tid >> 6, lane = tid & 63;
    int g = lane >> 4, lr = lane & 15;
    int row0 = (bid - 1024) * 64;
    // stage: 2048 chunks of 8 bf16, fully coalesced fp32 reads
    #pragma unroll
    for (int i = 0; i < 8; i++) {
      int c = i * 256 + tid;
      int ra = c >> 5, cc = c & 31;
      const float4* p = (const float4*)&m_data[(size_t)(row0 + ra) * DMODEL + cc * 8];
      *(ushort8*)&As[ra * ASTRIDE + cc * 8] = __builtin_bit_cast(ushort8, pack8(p[0], p[1]));
    }
    __syncthreads();
    // MFMA: wave w owns row-tile w (16 rows); A from LDS, B (wkv) from L1/L2
    f32x4 acc[4] = {};
    #pragma unroll
    for (int ks = 0; ks < 8; ks++) {
      bf16x8 af = ldfrag(&As[(wave * 16 + lr) * ASTRIDE + ks * 32 + g * 8]);
      #pragma unroll
      for (int ct = 0; ct < 4; ct++) {
        bf16x8 bf = ldfrag(&wkv[((ks * 4 + ct) << 9) + lane * 8]);
        acc[ct] = __builtin_amdgcn_mfma_f32_16x16x32_bf16(af, bf, acc[ct], 0, 0, 0);
      }
    }
    __syncthreads();  // all A reads done; safe to overwrite As with O
    unsigned short* O = As;
    #pragma unroll
    for (int ct = 0; ct < 4; ct++) {
      #pragma unroll
      for (int rg = 0; rg < 4; rg++) {
        O[(wave * 16 + g * 4 + rg) * OSTRIDE + ct * 16 + lr] = f2bf(acc[ct][rg]);  // D layout (m89)
      }
    }
    __syncthreads();
    // coalesced write-out: kb tile contiguous 4KB; vb_t tile 32 rows x 128B
    {
      int rowl = tid >> 2, c8 = (tid & 3) * 8;  // kb: cols 0..31
      ushort8 v = *(const ushort8*)&O[rowl * OSTRIDE + c8];
      *(ushort8*)&kb[(size_t)(row0 + rowl) * 32 + c8] = v;
    }
    {
      int d = tid >> 3, s8 = (tid & 7) * 8;     // vb_t: d 0..31, s-chunk of 8
      ushort8 v;
      #pragma unroll
      for (int j = 0; j < 8; j++) v[j] = O[(s8 + j) * OSTRIDE + 32 + d];
      int ra = row0 >> 10, sl0 = row0 & 1023;
      *(ushort8*)&vb_t[((size_t)(ra * 32) + d) * S_DIM + sl0 + s8] = v;
    }
  }
}

// ---------- attn2: pool2 (q projection) + QK^T MFMA + softmax + PV MFMA, one block per r ----------
__global__ __launch_bounds__(256) void attn2_kernel(const unsigned short* __restrict__ kb,
                                                    const unsigned short* __restrict__ vb_t,
                                                    const float* __restrict__ psum,
                                                    const float* __restrict__ pmask,
                                                    const float* __restrict__ Wq,
                                                    const float* __restrict__ bias,
                                                    float* __restrict__ wavg) {
  int r = blockIdx.x, tid = threadIdx.x;
  int w = tid >> 6, lane = tid & 63, g = lane >> 4, lr = lane & 15;
  __shared__ float qa[256];
  __shared__ float qsp[8 * 33];      // padded q[h][k]
  __shared__ float lgp[8 * 1028];    // padded logits/P [h][s]
  __shared__ float paccL[8 * 64 * 4];
  __shared__ float denom[8];
  // ---- pool2: q_avg -> q projection (qproj kept in LDS only) ----
  float s4 = psum[(r * 4 + 0) * 256 + tid] + psum[(r * 4 + 1) * 256 + tid] +
             psum[(r * 4 + 2) * 256 + tid] + psum[(r * 4 + 3) * 256 + tid];
  float msum = pmask[r * 4] + pmask[r * 4 + 1] + pmask[r * 4 + 2] + pmask[r * 4 + 3];
  qa[tid] = s4 / (msum + EPSV);
  __syncthreads();
  float qacc = 0.f;
  #pragma unroll 8
  for (int d = 0; d < 256; d++) qacc += qa[d] * Wq[d * 256 + tid];
  qsp[(tid >> 5) * 33 + (tid & 31)] = qacc * 0.17677669529663687f;  // h=tid>>5, k=tid&31
  __syncthreads();
  // ---- QK^T via MFMA: A = K rows [s][k], B = q [k][h] ----
  ushort8 uq;
  #pragma unroll
  for (int j = 0; j < 8; j++)
    uq[j] = (lr < 8) ? f2bf(qsp[lr * 33 + g * 8 + j]) : (unsigned short)0;
  bf16x8 qf = __builtin_bit_cast(bf16x8, uq);
  for (int i = 0; i < 16; i++) {
    int rt = w * 16 + i;
    bf16x8 af = ldfrag(&kb[((size_t)r * S_DIM + rt * 16 + lr) * 32 + g * 8]);
    f32x4 d4 = {};
    d4 = __builtin_amdgcn_mfma_f32_16x16x32_bf16(af, qf, d4, 0, 0, 0);
    if (lr < 8) {
      #pragma unroll
      for (int rg = 0; rg < 4; rg++) {
        int sv = rt * 16 + g * 4 + rg;   // D: row=s=(lane>>4)*4+reg, col=h=lane&15
        lgp[lr * 1028 + sv] = d4[rg] + bias[r * S_DIM + sv];
      }
    }
  }
  __syncthreads();
  // ---- softmax per head (wave w handles h = 2w, 2w+1) ----
  for (int hh = 0; hh < 2; hh++) {
    int h = w * 2 + hh;
    float mx = -1e30f;
    #pragma unroll
    for (int i = 0; i < 16; i++) mx = fmaxf(mx, lgp[h * 1028 + lane + i * 64]);
    for (int off = 32; off; off >>= 1) mx = fmaxf(mx, __shfl_xor(mx, off));
    float sum = 0.f;
    #pragma unroll
    for (int i = 0; i < 16; i++) {
      float e = __expf(lgp[h * 1028 + lane + i * 64] - mx);
      lgp[h * 1028 + lane + i * 64] = e;
      sum += e;
    }
    for (int off = 32; off; off >>= 1) sum += __shfl_xor(sum, off);
    if (lane == 0) denom[h] = sum;
  }
  __syncthreads();
  // ---- PV via MFMA: A = P [h][s], B = V_t [s][d]; wave w does ks = 8w..8w+7 ----
  f32x4 pv[2] = {};
  for (int kk = 0; kk < 8; kk++) {
    int ks = w * 8 + kk;
    bf16x8 pa;
    if (lr < 8) {
      const float4* pp = (const float4*)&lgp[lr * 1028 + ks * 32 + g * 8];
      pa = pack8(*(const float4*)&pp[0], *(const float4*)&pp[1]);
    } else {
      pa = __builtin_bit_cast(bf16x8, (ushort8)(unsigned short)0);
    }
    #pragma unroll
    for (int ct = 0; ct < 2; ct++) {
      bf16x8 vf = ldfrag(&vb_t[((size_t)(r * 32) + ct * 16 + lr) * S_DIM + ks * 32 + g * 8]);
      pv[ct] = __builtin_amdgcn_mfma_f32_16x16x32_bf16(pa, vf, pv[ct], 0, 0, 0);
    }
  }
  *(f32x4*)&paccL[((w * 2 + 0) * 64 + lane) * 4] = pv[0];
  *(f32x4*)&paccL[((w * 2 + 1) * 64 + lane) * 4] = pv[1];
  __syncthreads();
  // ---- cross-wave reduce + divide ----
  {
    int h = tid >> 5, d = tid & 31;
    int ct = d >> 4, l2 = (h >> 2) * 16 + (d & 15), rg = h & 3;
    float sum = 0.f;
    #pragma unroll
    for (int w4 = 0; w4 < 4; w4++) sum += paccL[((w4 * 2 + ct) * 64 + l2) * 4 + rg];
    wavg[r * 256 + tid] = __fdividef(sum, denom[h]);
  }
}

// ---------- gate3: 64-row tiles, B from L2 per k-step ----------
template <int USE_BF16>
__global__ __launch_bounds__(512, 4) void gate3_kernel(const float* __restrict__ q_data,
                                                       const unsigned short* __restrict__ qb16,
                                                       const unsigned short* __restrict__ wg,
                                                       const unsigned short* __restrict__ wo,
                                                       const float* __restrict__ bgv,
                                                       const float* __restrict__ bov,
                                                       const float* __restrict__ wavg,
                                                       float* __restrict__ outp) {
  __shared__ unsigned short AsG[64 * ASTRIDE];
  __shared__ float wavs[256];
  __shared__ float bgs[256];
  __shared__ float bos[256];
  int bid = blockIdx.x;
  int r = bid >> 4, sc = bid & 15;
  int tid = threadIdx.x;
  int wave = tid >> 6, lane = tid & 63, g = lane >> 4, lr = lane & 15;
  int row0g = r * S_DIM + sc * 64;
  if (tid < 256) {
    wavs[tid] = wavg[r * 256 + tid];
    bgs[tid] = bgv[tid];
    bos[tid] = bov[tid];
  }
  // stage A tile (64 rows x 256 bf16): 2048 x 16B chunks
  #pragma unroll
  for (int i = 0; i < 4; i++) {
    int c = i * 512 + tid;
    int ra = c >> 5, cc = c & 31;
    ushort8 v;
    if (USE_BF16) {
      v = *(const ushort8*)&qb16[(size_t)(row0g + ra) * DMODEL + cc * 8];
    } else {
      const float4* p = (const float4*)&q_data[(size_t)(row0g + ra) * DMODEL + cc * 8];
      v = __builtin_bit_cast(ushort8, pack8(p[0], p[1]));
    }
    *(ushort8*)&AsG[ra * ASTRIDE + cc * 8] = v;
  }
  __syncthreads();
  // GEMM1: X @ Wg ; wave owns ct = 2*wave, 2*wave+1; B streamed from L2
  f32x4 acc[4][2] = {};
  for (int ks = 0; ks < 8; ks++) {
    bf16x8 b0 = ldfrag(&wg[((ks * 16 + 2 * wave) << 9) + lane * 8]);
    bf16x8 b1 = ldfrag(&wg[((ks * 16 + 2 * wave + 1) << 9) + lane * 8]);
    bf16x8 af[4];
    #pragma unroll
    for (int rt = 0; rt < 4; rt++)
      af[rt] = ldfrag(&AsG[(rt * 16 + lr) * ASTRIDE + ks * 32 + g * 8]);
    #pragma unroll
    for (int rt = 0; rt < 4; rt++) {
      acc[rt][0] = __builtin_amdgcn_mfma_f32_16x16x32_bf16(af[rt], b0, acc[rt][0], 0, 0, 0);
      acc[rt][1] = __builtin_amdgcn_mfma_f32_16x16x32_bf16(af[rt], b1, acc[rt][1], 0, 0, 0);
    }
  }
  __syncthreads();  // all GEMM1 reads of AsG done
  // gating epilogue -> G overwrites AsG
  #pragma unroll
  for (int rt = 0; rt < 4; rt++) {
    #pragma unroll
    for (int c0 = 0; c0 < 2; c0++) {
      int col = (wave * 2 + c0) * 16 + lr;
      float wv = wavs[col];
      float bgc = bgs[col];
      #pragma unroll
      for (int rg = 0; rg < 4; rg++) {
        int row = rt * 16 + g * 4 + rg;
        float x = acc[rt][c0][rg] + bgc;
        float sg = __fdividef(1.0f, 1.0f + __expf(-x));
        AsG[row * ASTRIDE + col] = f2bf(sg * wv);
      }
    }
  }
  __syncthreads();
  // GEMM2: G @ Wo
  f32x4 acc2[4][2] = {};
  for (int ks = 0; ks < 8; ks++) {
    bf16x8 b0 = ldfrag(&wo[((ks * 16 + 2 * wave) << 9) + lane * 8]);
    bf16x8 b1 = ldfrag(&wo[((ks * 16 + 2 * wave + 1) << 9) + lane * 8]);
    bf16x8 af[4];
    #pragma unroll
    for (int rt = 0; rt < 4; rt++)
      af[rt] = ldfrag(&AsG[(rt * 16 + lr) * ASTRIDE + ks * 32 + g * 8]);
    #pragma unroll
    for (int rt = 0; rt < 4; rt++) {
      acc2[rt][0] = __builtin_amdgcn_mfma_f32_16x16x32_bf16(af[rt], b0, acc2[rt][0], 0, 0, 0);
      acc2[rt][1] = __builtin_amdgcn_mfma_f32_16x16x32_bf16(af[rt], b1, acc2[rt][1], 0, 0, 0);
    }
  }
  #pragma unroll
  for (int rt = 0; rt < 4; rt++) {
    #pragma unroll
    for (int c0 = 0; c0 < 2; c0++) {
      int col = (wave * 2 + c0) * 16 + lr;
      float boc = bos[col];
      #pragma unroll
      for (int rg = 0; rg < 4; rg++) {
        int row = rt * 16 + g * 4 + rg;
        outp[(size_t)(row0g + row) * DMODEL + col] = acc2[rt][c0][rg] + boc;
      }
    }
  }
}

extern "C" void kernel_launch(void* const* d_in, const int* in_sizes, int n_in,
                              void* d_out, int out_size, void* d_ws, size_t ws_size,
                              hipStream_t stream) {
  const float* q_data = (const float*)d_in[0];
  const float* m_data = (const float*)d_in[1];
  const float* q_mask = (const float*)d_in[2];
  const float* bias   = (const float*)d_in[3];
  const float* Wq     = (const float*)d_in[4];
  const float* Wk     = (const float*)d_in[5];
  const float* Wv     = (const float*)d_in[6];
  const float* Wo     = (const float*)d_in[7];
  const float* bo     = (const float*)d_in[8];
  const float* Wg     = (const float*)d_in[9];
  const float* bg     = (const float*)d_in[10];
  float* outp = (float*)d_out;

  char* ws = (char*)d_ws;
  unsigned short* kb      = (unsigned short*)(ws + 0);          // 16 MB
  unsigned short* vb_t    = (unsigned short*)(ws + 16777216);   // 16 MB (transposed [r][d][s])
  unsigned short* wkv     = (unsigned short*)(ws + 33554432);   // 32 KB
  unsigned short* wg_pack = (unsigned short*)(ws + 33587200);   // 128 KB
  unsigned short* wo_pack = (unsigned short*)(ws + 33718272);   // 128 KB
  float* psum  = (float*)(ws + 33849344);                       // 1 MB
  float* pmask = (float*)(ws + 34897920);                       // 4 KB
  float* wavg  = (float*)(ws + 35164160);                       // 256 KB
  const size_t QB16_OFF = 35651584;
  const size_t QB16_BYTES = (size_t)R_DIM * S_DIM * DMODEL * 2; // 134 MB
  bool use_echo = ws_size >= QB16_OFF + QB16_BYTES;
  unsigned short* qb16 = use_echo ? (unsigned short*)(ws + QB16_OFF) : nullptr;

  pack_all_kernel<<<576, 256, 0, stream>>>(Wk, Wv, Wg, Wo, wkv, wg_pack, wo_pack);
  if (use_echo)
    streams_kernel<1><<<5120, 256, 0, stream>>>(m_data, wkv, kb, vb_t, q_data, q_mask, psum, pmask, qb16);
  else
    streams_kernel<0><<<5120, 256, 0, stream>>>(m_data, wkv, kb, vb_t, q_data, q_mask, psum, pmask, nullptr);
  attn2_kernel<<<256, 256, 0, stream>>>(kb, vb_t, psum, pmask, Wq, bias, wavg);
  if (use_echo)
    gate3_kernel<1><<<4096, 512, 0, stream>>>(q_data, qb16, wg_pack, wo_pack, bg, bo, wavg, outp);
  else
    gate3_kernel<0><<<4096, 512, 0, stream>>>(q_data, nullptr, wg_pack, wo_pack, bg, bo, wavg, outp);
}